// Round 16
// baseline (375.494 us; speedup 1.0000x reference)
//
#include <hip/hip_runtime.h>

typedef _Float16 half_t;
typedef _Float16 f16x8 __attribute__((ext_vector_type(8)));
typedef _Float16 f16x4 __attribute__((ext_vector_type(4)));
typedef float f32x4 __attribute__((ext_vector_type(4)));
typedef unsigned long long u64;

#define NN 6144
#define IN_DIM 512
#define DD 256
#define OUT_DIM 128
#define SPLIT 2
#define JT 24        // j-tiles of 128 per slice (3072/128)
#define LOG2E 1.44269504088896340736f

__device__ __forceinline__ f32x4 mfma16(f16x8 a, f16x8 b, f32x4 c) {
  return __builtin_amdgcn_mfma_f32_16x16x32_f16(a, b, c, 0, 0, 0);
}

// LDS-drain barrier (P visibility across waves); vmcnt NOT drained.
#define LBAR() asm volatile("s_waitcnt lgkmcnt(0)\n\ts_barrier" ::: "memory")

// monotone float<->uint encoding for atomicMax on floats of any sign
__device__ __forceinline__ unsigned enc_f(float f) {
  unsigned b = __float_as_uint(f);
  return (b & 0x80000000u) ? ~b : (b | 0x80000000u);
}
__device__ __forceinline__ float dec_f(unsigned u) {
  return (u & 0x80000000u) ? __uint_as_float(u & 0x7fffffffu)
                           : __uint_as_float(~u);
}

// ---------------- fused convert: x (f32->f16) + weights (convert+transpose) ----------------
__global__ void cvt_kernel(const float* __restrict__ x,
                           const float* __restrict__ W0, const float* __restrict__ W1,
                           const float* __restrict__ W2, const float* __restrict__ pW,
                           half_t* __restrict__ xh, half_t* __restrict__ WT,
                           half_t* __restrict__ pWT, unsigned* __restrict__ e2mu) {
  int bx = blockIdx.x, t = threadIdx.x;
  if (bx < 3072) {
    int idx = (bx * 256 + t) * 4;
    float4 v = *(const float4*)(x + idx);
    f16x4 h;
    h[0] = (half_t)v.x; h[1] = (half_t)v.y; h[2] = (half_t)v.z; h[3] = (half_t)v.w;
    *(f16x4*)(xh + idx) = h;
    return;
  }
  int idx2 = bx - 3072;
  if (idx2 == 0 && t < 3) e2mu[t] = 0x00800000u;   // enc(-FLT_MAX)
  int y = idx2 >> 9;
  int idx = ((idx2 & 511) << 8) + t;
  if (y < 3) {
    const float* W = (y == 0) ? W0 : (y == 1) ? W1 : W2;
    int k = idx >> 8, n = idx & 255;
    WT[(size_t)y * DD * IN_DIM + (size_t)n * IN_DIM + k] = (half_t)W[idx];
  } else if (idx < DD * OUT_DIM) {
    int k = idx >> 7, o = idx & 127;
    pWT[(size_t)o * DD + k] = (half_t)pW[idx];
  }
}

// ---------------- GEMM1 + fused e-scores + fused e2-max ----------------
__global__ __launch_bounds__(256, 2) void gemm1_kernel(
    const half_t* __restrict__ xh, const half_t* __restrict__ WT,
    const float* __restrict__ as0, const float* __restrict__ as1, const float* __restrict__ as2,
    const float* __restrict__ ad0, const float* __restrict__ ad1, const float* __restrict__ ad2,
    half_t* __restrict__ hT, float* __restrict__ e1, float* __restrict__ e2,
    unsigned* __restrict__ e2mu) {
  int v = blockIdx.y;
  int i0 = blockIdx.x * 64;
  int t = threadIdx.x;
  int lane = t & 63, w = t >> 6;
  int lr = lane & 15, lg = lane >> 4;
  const half_t* Wv = WT + (size_t)v * DD * IN_DIM;
  const float* asv = (v == 0) ? as0 : (v == 1) ? as1 : as2;
  const float* adv = (v == 0) ? ad0 : (v == 1) ? ad1 : ad2;
  f32x4 acc[4][4] = {};
  for (int kt = 0; kt < 16; ++kt) {
    int k = kt * 32 + lg * 8;
    f16x8 af[4], bf[4];
#pragma unroll
    for (int mf = 0; mf < 4; ++mf)
      af[mf] = *(const f16x8*)(xh + (size_t)(i0 + mf * 16 + lr) * IN_DIM + k);
#pragma unroll
    for (int nf = 0; nf < 4; ++nf)
      bf[nf] = *(const f16x8*)(Wv + (size_t)(w * 64 + nf * 16 + lr) * IN_DIM + k);
#pragma unroll
    for (int mf = 0; mf < 4; ++mf)
#pragma unroll
      for (int nf = 0; nf < 4; ++nf)
        acc[mf][nf] = mfma16(af[mf], bf[nf], acc[mf][nf]);
  }
  __shared__ half_t tr[4][64 * 64];
  __shared__ float ep1[4][64], ep2[4][64];
  char* trw = (char*)tr[w];
#pragma unroll
  for (int mf = 0; mf < 4; ++mf)
#pragma unroll
    for (int nf = 0; nf < 4; ++nf)
#pragma unroll
      for (int r = 0; r < 4; ++r) {
        int dl = nf * 16 + lr;
        int il = mf * 16 + lg * 4 + r;
        unsigned addr = (unsigned)((dl * 128 + il * 2) ^ ((dl & 7) << 4));
        *(half_t*)(trw + addr) = (half_t)acc[mf][nf][r];
      }
  float as_c[4], ad_c[4];
#pragma unroll
  for (int nf = 0; nf < 4; ++nf) {
    int col = w * 64 + nf * 16 + lr;
    as_c[nf] = asv[col];
    ad_c[nf] = adv[col];
  }
#pragma unroll
  for (int mf = 0; mf < 4; ++mf)
#pragma unroll
    for (int r = 0; r < 4; ++r) {
      float p1 = 0.f, p2 = 0.f;
#pragma unroll
      for (int nf = 0; nf < 4; ++nf) {
        p1 = fmaf(acc[mf][nf][r], as_c[nf], p1);
        p2 = fmaf(acc[mf][nf][r], ad_c[nf], p2);
      }
      p1 += __shfl_xor(p1, 1); p1 += __shfl_xor(p1, 2);
      p1 += __shfl_xor(p1, 4); p1 += __shfl_xor(p1, 8);
      p2 += __shfl_xor(p2, 1); p2 += __shfl_xor(p2, 2);
      p2 += __shfl_xor(p2, 4); p2 += __shfl_xor(p2, 8);
      if (lr == 0) {
        int il = mf * 16 + lg * 4 + r;
        ep1[w][il] = p1;
        ep2[w][il] = p2;
      }
    }
  __syncthreads();
  half_t* hTv = hT + (size_t)v * DD * NN;
#pragma unroll
  for (int c = 0; c < 8; ++c) {
    unsigned addr = (unsigned)((lane * 128 + c * 16) ^ ((lane & 7) << 4));
    f16x8 val = *(const f16x8*)(trw + addr);
    *(f16x8*)(hTv + (size_t)(w * 64 + lane) * NN + i0 + c * 8) = val;
  }
  if (t < 64) {
    float e1v = LOG2E * (ep1[0][t] + ep1[1][t] + ep1[2][t] + ep1[3][t]);
    float e2v = LOG2E * (ep2[0][t] + ep2[1][t] + ep2[2][t] + ep2[3][t]);
    e1[v * NN + i0 + t] = e1v;
    e2[v * NN + i0 + t] = e2v;
    float m = e2v;
    m = fmaxf(m, __shfl_xor(m, 1));  m = fmaxf(m, __shfl_xor(m, 2));
    m = fmaxf(m, __shfl_xor(m, 4));  m = fmaxf(m, __shfl_xor(m, 8));
    m = fmaxf(m, __shfl_xor(m, 16)); m = fmaxf(m, __shfl_xor(m, 32));
    if (t == 0) atomicMax(e2mu + v, enc_f(m));
  }
}

// ---------------- fused GAT aggregation: 128-j tiles (half the tile count) ----------------
// grid (96, SPLIT, 3), 4 waves, 2 blocks/CU. Tile = 64 rows x 128 j.
// Per tile: comp_p -> LBAR (lgkm only) -> refill adj/e2 (depth ~1.5 regions)
// -> mfma with B gathered from L2 (r3-proven path). One barrier per tile;
// 13.8k block-tiles total (r15 had 27.6k) to amortize the per-tile serial cost.
__global__ __launch_bounds__(256, 2) void gat_kernel(
    const int* __restrict__ adj0, const int* __restrict__ adj1, const int* __restrict__ adj2,
    const half_t* __restrict__ hT,
    const float* __restrict__ e1g, const float* __restrict__ e2g,
    const unsigned* __restrict__ e2mu, half_t* __restrict__ pacc, float* __restrict__ pl) {
  int v = blockIdx.z, s = blockIdx.y;
  const int* __restrict__ adjv = (v == 0) ? adj0 : (v == 1) ? adj1 : adj2;
  int i0 = blockIdx.x * 64;
  int t = threadIdx.x;
  int lane = t & 63, w = t >> 6;
  int lr = lane & 15, lg = lane >> 4;
  int jq = t & 15, rg = t >> 4;

  __shared__ half_t P0[64 * 128];     // 16 KB
  __shared__ half_t P1[64 * 128];     // 16 KB

  const half_t* hTv = hT + (size_t)v * DD * NN;
  const float* e2v = e2g + v * NN;
  const int jbase = s * JT * 128;

  float e1r[4], mr[4];
  float e2mL = dec_f(e2mu[v]);
#pragma unroll
  for (int it = 0; it < 4; ++it) {
    float e1i = e1g[v * NN + i0 + it * 16 + rg];
    e1r[it] = e1i;
    float sm = e1i + e2mL;
    mr[it] = fmaxf(sm, 0.2f * sm);   // lrelu upper bound of row max (log2 units)
  }

  f32x4 acc[4][4] = {};
  float lpart[4] = {0.f, 0.f, 0.f, 0.f};

  auto load_adj = [&](int4 (&aw)[4][2], int jt) {
    int j0 = jbase + jt * 128;
#pragma unroll
    for (int it = 0; it < 4; ++it) {
      const int* ap = adjv + (size_t)(i0 + it * 16 + rg) * NN + j0 + jq * 4;
      aw[it][0] = *(const int4*)ap;
      aw[it][1] = *(const int4*)(ap + 64);
    }
  };
  auto load_e2 = [&](float4 (&e2q)[2], int jt) {
    int j0 = jbase + jt * 128;
    e2q[0] = *(const float4*)(e2v + j0 + jq * 4);
    e2q[1] = *(const float4*)(e2v + j0 + 64 + jq * 4);
  };
  auto comp_p = [&](const int4 (&aw)[4][2], const float4 (&e2q)[2], char* pb) {
#pragma unroll
    for (int jp = 0; jp < 2; ++jp) {
      float e2a[4] = {e2q[jp].x, e2q[jp].y, e2q[jp].z, e2q[jp].w};
#pragma unroll
      for (int it = 0; it < 4; ++it) {
        int il = it * 16 + rg;
        int a4[4] = {aw[it][jp].x, aw[it][jp].y, aw[it][jp].z, aw[it][jp].w};
        f16x4 ph;
        float ssum = 0.f;
#pragma unroll
        for (int c = 0; c < 4; ++c) {
          float s1 = e1r[it] + e2a[c];
          float u = fmaxf(s1, 0.2f * s1) - mr[it];
          float p = (a4[c] > 0) ? exp2f(u) : 0.f;
          ssum += p;
          ph[c] = (half_t)p;
        }
        lpart[it] += ssum;
        unsigned addr = (unsigned)(il * 256 + ((jp * 128 + jq * 8) ^ ((il & 15) << 4)));
        *(f16x4*)(pb + addr) = ph;
      }
    }
  };
  auto do_mfma = [&](const char* pb, int jt) {
    int j0 = jbase + jt * 128;
    __builtin_amdgcn_s_setprio(1);
#pragma unroll
    for (int kf = 0; kf < 4; ++kf) {
      f16x8 bfr[4];
#pragma unroll
      for (int nf = 0; nf < 4; ++nf)
        bfr[nf] = *(const f16x8*)(hTv + (size_t)(w * 64 + nf * 16 + lr) * NN +
                                  j0 + kf * 32 + lg * 8);
#pragma unroll
      for (int mf = 0; mf < 4; ++mf) {
        int row = mf * 16 + lr;
        unsigned pa_ = (unsigned)(row * 256 + ((kf * 64 + lg * 16) ^ ((row & 15) << 4)));
        f16x8 af = *(const f16x8*)(pb + pa_);
#pragma unroll
        for (int nf = 0; nf < 4; ++nf)
          acc[mf][nf] = mfma16(af, bfr[nf], acc[mf][nf]);
      }
    }
    __builtin_amdgcn_s_setprio(0);
  };

  int4 awA[4][2], awB[4][2];
  float4 e2A[2], e2B[2];

  // prologue: tiles 0 and 1 in flight
  load_adj(awA, 0); load_e2(e2A, 0);
  load_adj(awB, 1); load_e2(e2B, 1);

  for (int tt = 0; tt < JT; tt += 2) {
    // tile tt: P0
    comp_p(awA, e2A, (char*)P0);
    LBAR();
    if (tt + 2 < JT) { load_adj(awA, tt + 2); load_e2(e2A, tt + 2); }
    do_mfma((char*)P0, tt);
    // tile tt+1: P1
    comp_p(awB, e2B, (char*)P1);
    LBAR();
    if (tt + 3 < JT) { load_adj(awB, tt + 3); load_e2(e2B, tt + 3); }
    do_mfma((char*)P1, tt + 1);
  }

  // row sums: reduce over jq within each 16-lane group, write pl directly
  size_t sl = (size_t)v * SPLIT + s;
#pragma unroll
  for (int it = 0; it < 4; ++it) {
    float ssum = lpart[it];
    ssum += __shfl_xor(ssum, 1); ssum += __shfl_xor(ssum, 2);
    ssum += __shfl_xor(ssum, 4); ssum += __shfl_xor(ssum, 8);
    if (jq == 0) pl[sl * NN + i0 + it * 16 + rg] = ssum;
  }

  half_t* pa = pacc + sl * (size_t)NN * DD;
#pragma unroll
  for (int mf = 0; mf < 4; ++mf)
#pragma unroll
    for (int r = 0; r < 4; ++r) {
      int il = mf * 16 + lg * 4 + r;
#pragma unroll
      for (int nf = 0; nf < 4; ++nf)
        pa[(size_t)(i0 + il) * DD + w * 64 + nf * 16 + lr] = (half_t)acc[mf][nf][r];
    }
}

// ---------------- proj + LN + weighted combine (fused 2-slice combine) ----------------
__global__ __launch_bounds__(64) void proj_kernel(
    const half_t* __restrict__ pacc, const float* __restrict__ pl,
    const half_t* __restrict__ pWT,
    const float* __restrict__ proj_b, const float* __restrict__ ln_g,
    const float* __restrict__ ln_b, const float* __restrict__ alpha,
    float* __restrict__ out) {
  int i0 = blockIdx.x * 16;
  int t = threadIdx.x;
  int lr = t & 15, lg = t >> 4;
  float a0 = alpha[0], a1 = alpha[1], a2 = alpha[2];
  float am = fmaxf(a0, fmaxf(a1, a2));
  float x0 = __expf(a0 - am), x1 = __expf(a1 - am), x2 = __expf(a2 - am);
  float inv = 1.f / (x0 + x1 + x2);
  float wv[3] = {x0 * inv, x1 * inv, x2 * inv};
  __shared__ float rlv[3][16];
  if (t < 48) {
    int v = t >> 4, i = t & 15;
    float l = pl[((size_t)v * SPLIT + 0) * NN + i0 + i] +
              pl[((size_t)v * SPLIT + 1) * NN + i0 + i];
    rlv[v][i] = (l > 0.f) ? 1.f / l : 0.f;
  }
  float pb[8], gg[8], bb[8];
#pragma unroll
  for (int nf = 0; nf < 8; ++nf) {
    pb[nf] = proj_b[nf * 16 + lr];
    gg[nf] = ln_g[nf * 16 + lr];
    bb[nf] = ln_b[nf * 16 + lr];
  }
  __syncthreads();
  f32x4 zacc[8] = {};
  for (int v = 0; v < 3; ++v) {
    float rl = rlv[v][lr];
    f32x4 yac[8] = {};
    const half_t* p0 = pacc + (((size_t)v * SPLIT + 0) * NN + i0 + lr) * DD;
    const half_t* p1 = pacc + (((size_t)v * SPLIT + 1) * NN + i0 + lr) * DD;
    for (int kt = 0; kt < 8; ++kt) {
      int k = kt * 32 + lg * 8;
      f16x8 s0 = *(const f16x8*)(p0 + k);
      f16x8 s1 = *(const f16x8*)(p1 + k);
      f16x8 af;
#pragma unroll
      for (int e = 0; e < 8; ++e)
        af[e] = (half_t)(((float)s0[e] + (float)s1[e]) * rl);
#pragma unroll
      for (int nf = 0; nf < 8; ++nf) {
        f16x8 bf = *(const f16x8*)(pWT + (size_t)(nf * 16 + lr) * DD + k);
        yac[nf] = mfma16(af, bf, yac[nf]);
      }
    }
#pragma unroll
    for (int r = 0; r < 4; ++r) {
      float ssum = 0.f, q = 0.f;
#pragma unroll
      for (int nf = 0; nf < 8; ++nf) {
        float y = yac[nf][r] + pb[nf];
        yac[nf][r] = y;
        ssum += y; q += y * y;
      }
      ssum += __shfl_xor(ssum, 1); ssum += __shfl_xor(ssum, 2);
      ssum += __shfl_xor(ssum, 4); ssum += __shfl_xor(ssum, 8);
      q += __shfl_xor(q, 1); q += __shfl_xor(q, 2);
      q += __shfl_xor(q, 4); q += __shfl_xor(q, 8);
      float mean = ssum * (1.f / 128.f);
      float var = q * (1.f / 128.f) - mean * mean;
      float rstd = rsqrtf(var + 1e-5f);
      float wvv = wv[v];
#pragma unroll
      for (int nf = 0; nf < 8; ++nf)
        zacc[nf][r] += wvv * (yac[nf][r] - mean) * rstd;
    }
  }
#pragma unroll
  for (int nf = 0; nf < 8; ++nf)
#pragma unroll
    for (int r = 0; r < 4; ++r) {
      int row = i0 + lg * 4 + r;
      float z = zacc[nf][r] * gg[nf] + bb[nf];
      if (!isfinite(z)) z = 0.f;
      out[(size_t)row * OUT_DIM + nf * 16 + lr] = z;
    }
  if (blockIdx.x == 0 && t < 3) out[(size_t)NN * OUT_DIM + t] = wv[t];
}

// ---------------- launch ----------------
extern "C" void kernel_launch(void* const* d_in, const int* in_sizes, int n_in,
                              void* d_out, int out_size, void* d_ws, size_t ws_size,
                              hipStream_t stream) {
  const float* x      = (const float*)d_in[0];
  const int*   adj_cf = (const int*)d_in[1];
  const int*   adj_or = (const int*)d_in[2];
  const int*   adj_pe = (const int*)d_in[3];
  const float* W_cf   = (const float*)d_in[4];
  const float* as_cf  = (const float*)d_in[5];
  const float* ad_cf  = (const float*)d_in[6];
  const float* W_or   = (const float*)d_in[7];
  const float* as_or  = (const float*)d_in[8];
  const float* ad_or  = (const float*)d_in[9];
  const float* W_pe   = (const float*)d_in[10];
  const float* as_pe  = (const float*)d_in[11];
  const float* ad_pe  = (const float*)d_in[12];
  const float* proj_W = (const float*)d_in[13];
  const float* proj_b = (const float*)d_in[14];
  const float* ln_g   = (const float*)d_in[15];
  const float* ln_b   = (const float*)d_in[16];
  const float* alpha  = (const float*)d_in[17];

  char* ws = (char*)d_ws;
  half_t*   xh     = (half_t*)(ws + 0);          // 6291456
  half_t*   WT     = (half_t*)(ws + 6291456);    // 786432
  half_t*   pWT    = (half_t*)(ws + 7077888);    // 65536
  half_t*   hT     = (half_t*)(ws + 7143424);    // 9437184
  float*    e1     = (float*)(ws + 16580608);    // 73728
  float*    e2     = (float*)(ws + 16654336);    // 73728
  unsigned* e2mu   = (unsigned*)(ws + 16728064); // 64
  half_t*   pacc   = (half_t*)(ws + 16728128);   // 3*2*6144*256*2 = 18874368
  float*    pl     = (float*)(ws + 35602496);    // 3*2*6144*4 = 147456

  cvt_kernel<<<5120, 256, 0, stream>>>(x, W_cf, W_or, W_pe, proj_W, xh, WT, pWT, e2mu);
  gemm1_kernel<<<dim3(96, 3), 256, 0, stream>>>(xh, WT, as_cf, as_or, as_pe,
                                                ad_cf, ad_or, ad_pe, hT, e1, e2, e2mu);
  gat_kernel<<<dim3(96, SPLIT, 3), 256, 0, stream>>>(adj_cf, adj_or, adj_pe, hT,
                                                     e1, e2, e2mu, pacc, pl);
  proj_kernel<<<384, 64, 0, stream>>>(pacc, pl, pWT, proj_b, ln_g, ln_b, alpha,
                                      (float*)d_out);
}

// Round 17
// 233.221 us; speedup vs baseline: 1.6100x; 1.6100x over previous
//
#include <hip/hip_runtime.h>

typedef _Float16 half_t;
typedef _Float16 f16x8 __attribute__((ext_vector_type(8)));
typedef _Float16 f16x4 __attribute__((ext_vector_type(4)));
typedef float f32x4 __attribute__((ext_vector_type(4)));
typedef unsigned long long u64;

#define NN 6144
#define IN_DIM 512
#define DD 256
#define OUT_DIM 128
#define SPLIT 4
#define JT 24        // j-tiles of 64 per slice (1536/64)
#define LOG2E 1.44269504088896340736f

__device__ __forceinline__ f32x4 mfma16(f16x8 a, f16x8 b, f32x4 c) {
  return __builtin_amdgcn_mfma_f32_16x16x32_f16(a, b, c, 0, 0, 0);
}

// LDS-drain barrier (P visibility across waves); vmcnt NOT drained.
#define LBAR() asm volatile("s_waitcnt lgkmcnt(0)\n\ts_barrier" ::: "memory")
// counted vmem wait (no memory clobber; order pinned by sched_barrier)
#define VWAIT(N) asm volatile("s_waitcnt vmcnt(" #N ")")
#define SBAR() __builtin_amdgcn_sched_barrier(0)

// monotone float<->uint encoding for atomicMax on floats of any sign
__device__ __forceinline__ unsigned enc_f(float f) {
  unsigned b = __float_as_uint(f);
  return (b & 0x80000000u) ? ~b : (b | 0x80000000u);
}
__device__ __forceinline__ float dec_f(unsigned u) {
  return (u & 0x80000000u) ? __uint_as_float(u & 0x7fffffffu)
                           : __uint_as_float(~u);
}

// ---------------- fused convert: x (f32->f16) + weights (convert+transpose) ----------------
__global__ void cvt_kernel(const float* __restrict__ x,
                           const float* __restrict__ W0, const float* __restrict__ W1,
                           const float* __restrict__ W2, const float* __restrict__ pW,
                           half_t* __restrict__ xh, half_t* __restrict__ WT,
                           half_t* __restrict__ pWT, unsigned* __restrict__ e2mu) {
  int bx = blockIdx.x, t = threadIdx.x;
  if (bx < 3072) {
    int idx = (bx * 256 + t) * 4;
    float4 v = *(const float4*)(x + idx);
    f16x4 h;
    h[0] = (half_t)v.x; h[1] = (half_t)v.y; h[2] = (half_t)v.z; h[3] = (half_t)v.w;
    *(f16x4*)(xh + idx) = h;
    return;
  }
  int idx2 = bx - 3072;
  if (idx2 == 0 && t < 3) e2mu[t] = 0x00800000u;   // enc(-FLT_MAX)
  int y = idx2 >> 9;
  int idx = ((idx2 & 511) << 8) + t;
  if (y < 3) {
    const float* W = (y == 0) ? W0 : (y == 1) ? W1 : W2;
    int k = idx >> 8, n = idx & 255;
    WT[(size_t)y * DD * IN_DIM + (size_t)n * IN_DIM + k] = (half_t)W[idx];
  } else if (idx < DD * OUT_DIM) {
    int k = idx >> 7, o = idx & 127;
    pWT[(size_t)o * DD + k] = (half_t)pW[idx];
  }
}

// ---------------- GEMM1 + fused e-scores + fused e2-max ----------------
__global__ __launch_bounds__(256, 2) void gemm1_kernel(
    const half_t* __restrict__ xh, const half_t* __restrict__ WT,
    const float* __restrict__ as0, const float* __restrict__ as1, const float* __restrict__ as2,
    const float* __restrict__ ad0, const float* __restrict__ ad1, const float* __restrict__ ad2,
    half_t* __restrict__ hT, float* __restrict__ e1, float* __restrict__ e2,
    unsigned* __restrict__ e2mu) {
  int v = blockIdx.y;
  int i0 = blockIdx.x * 64;
  int t = threadIdx.x;
  int lane = t & 63, w = t >> 6;
  int lr = lane & 15, lg = lane >> 4;
  const half_t* Wv = WT + (size_t)v * DD * IN_DIM;
  const float* asv = (v == 0) ? as0 : (v == 1) ? as1 : as2;
  const float* adv = (v == 0) ? ad0 : (v == 1) ? ad1 : ad2;
  f32x4 acc[4][4] = {};
  for (int kt = 0; kt < 16; ++kt) {
    int k = kt * 32 + lg * 8;
    f16x8 af[4], bf[4];
#pragma unroll
    for (int mf = 0; mf < 4; ++mf)
      af[mf] = *(const f16x8*)(xh + (size_t)(i0 + mf * 16 + lr) * IN_DIM + k);
#pragma unroll
    for (int nf = 0; nf < 4; ++nf)
      bf[nf] = *(const f16x8*)(Wv + (size_t)(w * 64 + nf * 16 + lr) * IN_DIM + k);
#pragma unroll
    for (int mf = 0; mf < 4; ++mf)
#pragma unroll
      for (int nf = 0; nf < 4; ++nf)
        acc[mf][nf] = mfma16(af[mf], bf[nf], acc[mf][nf]);
  }
  __shared__ half_t tr[4][64 * 64];
  __shared__ float ep1[4][64], ep2[4][64];
  char* trw = (char*)tr[w];
#pragma unroll
  for (int mf = 0; mf < 4; ++mf)
#pragma unroll
    for (int nf = 0; nf < 4; ++nf)
#pragma unroll
      for (int r = 0; r < 4; ++r) {
        int dl = nf * 16 + lr;
        int il = mf * 16 + lg * 4 + r;
        unsigned addr = (unsigned)((dl * 128 + il * 2) ^ ((dl & 7) << 4));
        *(half_t*)(trw + addr) = (half_t)acc[mf][nf][r];
      }
  float as_c[4], ad_c[4];
#pragma unroll
  for (int nf = 0; nf < 4; ++nf) {
    int col = w * 64 + nf * 16 + lr;
    as_c[nf] = asv[col];
    ad_c[nf] = adv[col];
  }
#pragma unroll
  for (int mf = 0; mf < 4; ++mf)
#pragma unroll
    for (int r = 0; r < 4; ++r) {
      float p1 = 0.f, p2 = 0.f;
#pragma unroll
      for (int nf = 0; nf < 4; ++nf) {
        p1 = fmaf(acc[mf][nf][r], as_c[nf], p1);
        p2 = fmaf(acc[mf][nf][r], ad_c[nf], p2);
      }
      p1 += __shfl_xor(p1, 1); p1 += __shfl_xor(p1, 2);
      p1 += __shfl_xor(p1, 4); p1 += __shfl_xor(p1, 8);
      p2 += __shfl_xor(p2, 1); p2 += __shfl_xor(p2, 2);
      p2 += __shfl_xor(p2, 4); p2 += __shfl_xor(p2, 8);
      if (lr == 0) {
        int il = mf * 16 + lg * 4 + r;
        ep1[w][il] = p1;
        ep2[w][il] = p2;
      }
    }
  __syncthreads();
  half_t* hTv = hT + (size_t)v * DD * NN;
#pragma unroll
  for (int c = 0; c < 8; ++c) {
    unsigned addr = (unsigned)((lane * 128 + c * 16) ^ ((lane & 7) << 4));
    f16x8 val = *(const f16x8*)(trw + addr);
    *(f16x8*)(hTv + (size_t)(w * 64 + lane) * NN + i0 + c * 8) = val;
  }
  if (t < 64) {
    float e1v = LOG2E * (ep1[0][t] + ep1[1][t] + ep1[2][t] + ep1[3][t]);
    float e2v = LOG2E * (ep2[0][t] + ep2[1][t] + ep2[2][t] + ep2[3][t]);
    e1[v * NN + i0 + t] = e1v;
    e2[v * NN + i0 + t] = e2v;
    float m = e2v;
    m = fmaxf(m, __shfl_xor(m, 1));  m = fmaxf(m, __shfl_xor(m, 2));
    m = fmaxf(m, __shfl_xor(m, 4));  m = fmaxf(m, __shfl_xor(m, 8));
    m = fmaxf(m, __shfl_xor(m, 16)); m = fmaxf(m, __shfl_xor(m, 32));
    if (t == 0) atomicMax(e2mu + v, enc_f(m));
  }
}

// ---------------- fused GAT aggregation: counted-vmcnt pipeline + XCD swizzle ----------------
// 1D grid 1152 blocks (= 96 x SPLIT x 3), 4 waves, 2 blocks/CU.
// Chunked bijective XCD swizzle: each XCD gets 144 contiguous blocks ~ one
// (v,s) group, so that view's 3.1 MB hT slice stays resident in its 4 MB L2.
__global__ __launch_bounds__(256, 2) void gat_kernel(
    const int* __restrict__ adj0, const int* __restrict__ adj1, const int* __restrict__ adj2,
    const half_t* __restrict__ hT,
    const float* __restrict__ e1g, const float* __restrict__ e2g,
    const unsigned* __restrict__ e2mu, half_t* __restrict__ pacc, float* __restrict__ pl) {
  // XCD-aware remap (1152 % 8 == 0 -> bijective)
  int orig = blockIdx.x;
  int swz = (orig & 7) * 144 + (orig >> 3);
  int v = swz / (96 * SPLIT);
  int rem = swz - v * (96 * SPLIT);
  int s = rem / 96;
  int i0 = (rem - s * 96) * 64;

  const int* __restrict__ adjv = (v == 0) ? adj0 : (v == 1) ? adj1 : adj2;
  int t = threadIdx.x;
  int lane = t & 63, w = t >> 6;
  int lr = lane & 15, lg = lane >> 4;
  int jq = t & 15, rg = t >> 4;

  __shared__ half_t hbuf0[DD * 64];   // 32 KB
  __shared__ half_t hbuf1[DD * 64];   // 32 KB
  __shared__ half_t P0[64 * 64];      // 8 KB
  __shared__ half_t P1[64 * 64];      // 8 KB

  const half_t* hTv = hT + (size_t)v * DD * NN;
  const float* e2v = e2g + v * NN;
  const int jbase = s * JT * 64;

  float e1r[4], mr[4];
  float e2mL = dec_f(e2mu[v]);
#pragma unroll
  for (int it = 0; it < 4; ++it) {
    float e1i = e1g[v * NN + i0 + it * 16 + rg];
    e1r[it] = e1i;
    float sm = e1i + e2mL;
    mr[it] = fmaxf(sm, 0.2f * sm);   // lrelu upper bound of row max (log2 units)
  }

  f32x4 acc[4][4] = {};
  float lpart[4] = {0.f, 0.f, 0.f, 0.f};

  int sub = lane >> 3;
  int c_src = (lane & 7) ^ sub;
  auto gload = [&](half_t* hb, int jt) {
    int j0 = jbase + jt * 64;
#pragma unroll
    for (int q = 0; q < 8; ++q) {
      const half_t* gp = hTv + (size_t)(w * 64 + q * 8 + sub) * NN + j0 + c_src * 8;
      half_t* lp = hb + (w * 8 + q) * 512;
      __builtin_amdgcn_global_load_lds(
          (const __attribute__((address_space(1))) int*)gp,
          (__attribute__((address_space(3))) int*)lp, 16, 0, 0);
    }
  };
  auto load_adj = [&](int4 (&aw)[4], int jt) {
    int j0 = jbase + jt * 64;
#pragma unroll
    for (int it = 0; it < 4; ++it)
      aw[it] = *(const int4*)(adjv + (size_t)(i0 + it * 16 + rg) * NN + j0 + jq * 4);
  };
  auto comp_p = [&](const int4 (&aw)[4], const float4& e2q, char* pb) {
    float e2a[4] = {e2q.x, e2q.y, e2q.z, e2q.w};
#pragma unroll
    for (int it = 0; it < 4; ++it) {
      int il = it * 16 + rg;
      int a4[4] = {aw[it].x, aw[it].y, aw[it].z, aw[it].w};
      f16x4 ph;
      float ssum = 0.f;
#pragma unroll
      for (int c = 0; c < 4; ++c) {
        float s1 = e1r[it] + e2a[c];
        float u = fmaxf(s1, 0.2f * s1) - mr[it];
        float p = (a4[c] > 0) ? exp2f(u) : 0.f;
        ssum += p;
        ph[c] = (half_t)p;
      }
      lpart[it] += ssum;
      unsigned addr = (unsigned)((il * 128 + jq * 8) ^ ((il & 7) << 4));
      *(f16x4*)(pb + addr) = ph;
    }
  };
  auto do_mfma = [&](const char* pb, const half_t* hb) {
    __builtin_amdgcn_s_setprio(1);
#pragma unroll
    for (int kf = 0; kf < 2; ++kf) {
      f16x8 bfr[4];
#pragma unroll
      for (int nf = 0; nf < 4; ++nf) {
        int d = w * 64 + nf * 16 + lr;
        unsigned ba = (unsigned)(d * 128 + ((kf * 64 + lg * 16) ^ ((lr & 7) << 4)));
        bfr[nf] = *(const f16x8*)((const char*)hb + ba);
      }
#pragma unroll
      for (int mf = 0; mf < 4; ++mf) {
        int row = mf * 16 + lr;
        unsigned pa_ = (unsigned)((row * 128 + kf * 64 + lg * 16) ^ ((row & 7) << 4));
        f16x8 af = *(const f16x8*)(pb + pa_);
#pragma unroll
        for (int nf = 0; nf < 4; ++nf)
          acc[mf][nf] = mfma16(af, bfr[nf], acc[mf][nf]);
      }
    }
    __builtin_amdgcn_s_setprio(0);
  };

  int4 awA[4], awB[4];
  float4 e2A, e2B;

  // prologue: adj(0)/e2(0) FIRST (oldest), then gload(0), then adj(1)/e2(1).
  load_adj(awA, 0);
  e2A = *(const float4*)(e2v + jbase + jq * 4);
  SBAR();
  gload(hbuf0, 0);
  SBAR();
  load_adj(awB, 1);
  e2B = *(const float4*)(e2v + jbase + 64 + jq * 4);
  SBAR();

  // full region: consume tile T (adj in AWc, P in Pc, hT in Hc);
  // refill AWc/E2c with tile T+2; stage hT(T+1) into Hn.
#define REGION_F(T, AWc, E2c, Pc, Hc, Hn)                            \
  {                                                                  \
    comp_p(AWc, E2c, (char*)(Pc));                                   \
    LBAR();                                                          \
    SBAR();                                                          \
    VWAIT(5);                                                        \
    SBAR();                                                          \
    gload(Hn, (T) + 1);                                              \
    SBAR();                                                          \
    load_adj(AWc, (T) + 2);                                          \
    E2c = *(const float4*)(e2v + jbase + ((T) + 2) * 64 + jq * 4);   \
    SBAR();                                                          \
    do_mfma((char*)(Pc), Hc);                                        \
  }

  for (int tt = 0; tt < JT - 2; tt += 2) {
    REGION_F(tt,     awA, e2A, P0, hbuf0, hbuf1);
    REGION_F(tt + 1, awB, e2B, P1, hbuf1, hbuf0);
  }
  // region JT-2: stage gload(JT-1); no adj refill.
  {
    comp_p(awA, e2A, (char*)P0);
    LBAR();
    SBAR();
    VWAIT(5);
    SBAR();
    gload(hbuf1, JT - 1);
    SBAR();
    do_mfma((char*)P0, hbuf0);
  }
  // region JT-1: drain fully.
  {
    comp_p(awB, e2B, (char*)P1);
    LBAR();
    SBAR();
    VWAIT(0);
    SBAR();
    do_mfma((char*)P1, hbuf1);
  }
#undef REGION_F

  // row sums: reduce over jq within each 16-lane group, write pl directly
  size_t sl = (size_t)v * SPLIT + s;
#pragma unroll
  for (int it = 0; it < 4; ++it) {
    float ssum = lpart[it];
    ssum += __shfl_xor(ssum, 1); ssum += __shfl_xor(ssum, 2);
    ssum += __shfl_xor(ssum, 4); ssum += __shfl_xor(ssum, 8);
    if (jq == 0) pl[sl * NN + i0 + it * 16 + rg] = ssum;
  }

  half_t* pa = pacc + sl * (size_t)NN * DD;
#pragma unroll
  for (int mf = 0; mf < 4; ++mf)
#pragma unroll
    for (int r = 0; r < 4; ++r) {
      int il = mf * 16 + lg * 4 + r;
#pragma unroll
      for (int nf = 0; nf < 4; ++nf)
        pa[(size_t)(i0 + il) * DD + w * 64 + nf * 16 + lr] = (half_t)acc[mf][nf][r];
    }
}

// ---------------- proj + LN + weighted combine (fused slice-combine) ----------------
__global__ __launch_bounds__(64) void proj_kernel(
    const half_t* __restrict__ pacc, const float* __restrict__ pl,
    const half_t* __restrict__ pWT,
    const float* __restrict__ proj_b, const float* __restrict__ ln_g,
    const float* __restrict__ ln_b, const float* __restrict__ alpha,
    float* __restrict__ out) {
  int i0 = blockIdx.x * 16;
  int t = threadIdx.x;
  int lr = t & 15, lg = t >> 4;
  float a0 = alpha[0], a1 = alpha[1], a2 = alpha[2];
  float am = fmaxf(a0, fmaxf(a1, a2));
  float x0 = __expf(a0 - am), x1 = __expf(a1 - am), x2 = __expf(a2 - am);
  float inv = 1.f / (x0 + x1 + x2);
  float wv[3] = {x0 * inv, x1 * inv, x2 * inv};
  __shared__ float rlv[3][16];
  if (t < 48) {
    int v = t >> 4, i = t & 15;
    float l = 0.f;
#pragma unroll
    for (int s = 0; s < SPLIT; ++s)
      l += pl[((size_t)v * SPLIT + s) * NN + i0 + i];
    rlv[v][i] = (l > 0.f) ? 1.f / l : 0.f;
  }
  float pb[8], gg[8], bb[8];
#pragma unroll
  for (int nf = 0; nf < 8; ++nf) {
    pb[nf] = proj_b[nf * 16 + lr];
    gg[nf] = ln_g[nf * 16 + lr];
    bb[nf] = ln_b[nf * 16 + lr];
  }
  __syncthreads();
  f32x4 zacc[8] = {};
  for (int v = 0; v < 3; ++v) {
    float rl = rlv[v][lr];
    f32x4 yac[8] = {};
    const half_t* p0 = pacc + (((size_t)v * SPLIT + 0) * NN + i0 + lr) * DD;
    const half_t* p1 = pacc + (((size_t)v * SPLIT + 1) * NN + i0 + lr) * DD;
    const half_t* p2 = pacc + (((size_t)v * SPLIT + 2) * NN + i0 + lr) * DD;
    const half_t* p3 = pacc + (((size_t)v * SPLIT + 3) * NN + i0 + lr) * DD;
    for (int kt = 0; kt < 8; ++kt) {
      int k = kt * 32 + lg * 8;
      f16x8 s0 = *(const f16x8*)(p0 + k);
      f16x8 s1 = *(const f16x8*)(p1 + k);
      f16x8 s2 = *(const f16x8*)(p2 + k);
      f16x8 s3 = *(const f16x8*)(p3 + k);
      f16x8 af;
#pragma unroll
      for (int e = 0; e < 8; ++e)
        af[e] = (half_t)((((float)s0[e] + (float)s1[e]) +
                          ((float)s2[e] + (float)s3[e])) * rl);
#pragma unroll
      for (int nf = 0; nf < 8; ++nf) {
        f16x8 bf = *(const f16x8*)(pWT + (size_t)(nf * 16 + lr) * DD + k);
        yac[nf] = mfma16(af, bf, yac[nf]);
      }
    }
#pragma unroll
    for (int r = 0; r < 4; ++r) {
      float ssum = 0.f, q = 0.f;
#pragma unroll
      for (int nf = 0; nf < 8; ++nf) {
        float y = yac[nf][r] + pb[nf];
        yac[nf][r] = y;
        ssum += y; q += y * y;
      }
      ssum += __shfl_xor(ssum, 1); ssum += __shfl_xor(ssum, 2);
      ssum += __shfl_xor(ssum, 4); ssum += __shfl_xor(ssum, 8);
      q += __shfl_xor(q, 1); q += __shfl_xor(q, 2);
      q += __shfl_xor(q, 4); q += __shfl_xor(q, 8);
      float mean = ssum * (1.f / 128.f);
      float var = q * (1.f / 128.f) - mean * mean;
      float rstd = rsqrtf(var + 1e-5f);
      float wvv = wv[v];
#pragma unroll
      for (int nf = 0; nf < 8; ++nf)
        zacc[nf][r] += wvv * (yac[nf][r] - mean) * rstd;
    }
  }
#pragma unroll
  for (int nf = 0; nf < 8; ++nf)
#pragma unroll
    for (int r = 0; r < 4; ++r) {
      int row = i0 + lg * 4 + r;
      float z = zacc[nf][r] * gg[nf] + bb[nf];
      if (!isfinite(z)) z = 0.f;
      out[(size_t)row * OUT_DIM + nf * 16 + lr] = z;
    }
  if (blockIdx.x == 0 && t < 3) out[(size_t)NN * OUT_DIM + t] = wv[t];
}

// ---------------- launch ----------------
extern "C" void kernel_launch(void* const* d_in, const int* in_sizes, int n_in,
                              void* d_out, int out_size, void* d_ws, size_t ws_size,
                              hipStream_t stream) {
  const float* x      = (const float*)d_in[0];
  const int*   adj_cf = (const int*)d_in[1];
  const int*   adj_or = (const int*)d_in[2];
  const int*   adj_pe = (const int*)d_in[3];
  const float* W_cf   = (const float*)d_in[4];
  const float* as_cf  = (const float*)d_in[5];
  const float* ad_cf  = (const float*)d_in[6];
  const float* W_or   = (const float*)d_in[7];
  const float* as_or  = (const float*)d_in[8];
  const float* ad_or  = (const float*)d_in[9];
  const float* W_pe   = (const float*)d_in[10];
  const float* as_pe  = (const float*)d_in[11];
  const float* ad_pe  = (const float*)d_in[12];
  const float* proj_W = (const float*)d_in[13];
  const float* proj_b = (const float*)d_in[14];
  const float* ln_g   = (const float*)d_in[15];
  const float* ln_b   = (const float*)d_in[16];
  const float* alpha  = (const float*)d_in[17];

  char* ws = (char*)d_ws;
  half_t*   xh     = (half_t*)(ws + 0);          // 6291456
  half_t*   WT     = (half_t*)(ws + 6291456);    // 786432
  half_t*   pWT    = (half_t*)(ws + 7077888);    // 65536
  half_t*   hT     = (half_t*)(ws + 7143424);    // 9437184
  float*    e1     = (float*)(ws + 16580608);    // 73728
  float*    e2     = (float*)(ws + 16654336);    // 73728
  unsigned* e2mu   = (unsigned*)(ws + 16728064); // 64
  half_t*   pacc   = (half_t*)(ws + 16728128);   // 37748736
  float*    pl     = (float*)(ws + 54476864);    // 294912

  cvt_kernel<<<5120, 256, 0, stream>>>(x, W_cf, W_or, W_pe, proj_W, xh, WT, pWT, e2mu);
  gemm1_kernel<<<dim3(96, 3), 256, 0, stream>>>(xh, WT, as_cf, as_or, as_pe,
                                                ad_cf, ad_or, ad_pe, hT, e1, e2, e2mu);
  gat_kernel<<<96 * SPLIT * 3, 256, 0, stream>>>(adj_cf, adj_or, adj_pe, hT,
                                                 e1, e2, e2mu, pacc, pl);
  proj_kernel<<<384, 64, 0, stream>>>(pacc, pl, pWT, proj_b, ln_g, ln_b, alpha,
                                      (float*)d_out);
}

// Round 18
// 224.448 us; speedup vs baseline: 1.6730x; 1.0391x over previous
//
#include <hip/hip_runtime.h>

typedef _Float16 half_t;
typedef _Float16 f16x8 __attribute__((ext_vector_type(8)));
typedef _Float16 f16x4 __attribute__((ext_vector_type(4)));
typedef float f32x4 __attribute__((ext_vector_type(4)));
typedef unsigned long long u64;

#define NN 6144
#define IN_DIM 512
#define DD 256
#define OUT_DIM 128
#define SPLIT 4
#define JT 24        // j-tiles of 64 per slice (1536/64)
#define LOG2E 1.44269504088896340736f

__device__ __forceinline__ f32x4 mfma16(f16x8 a, f16x8 b, f32x4 c) {
  return __builtin_amdgcn_mfma_f32_16x16x32_f16(a, b, c, 0, 0, 0);
}

// LDS-drain barrier (P visibility across waves); vmcnt NOT drained.
#define LBAR() asm volatile("s_waitcnt lgkmcnt(0)\n\ts_barrier" ::: "memory")
// counted vmem wait (no memory clobber; order pinned by sched_barrier)
#define VWAIT(N) asm volatile("s_waitcnt vmcnt(" #N ")")
#define SBAR() __builtin_amdgcn_sched_barrier(0)

// monotone float<->uint encoding for atomicMax on floats of any sign
__device__ __forceinline__ unsigned enc_f(float f) {
  unsigned b = __float_as_uint(f);
  return (b & 0x80000000u) ? ~b : (b | 0x80000000u);
}
__device__ __forceinline__ float dec_f(unsigned u) {
  return (u & 0x80000000u) ? __uint_as_float(u & 0x7fffffffu)
                           : __uint_as_float(~u);
}

// ---------------- fused convert: x (f32->f16) + weights (convert+transpose) ----------------
__global__ void cvt_kernel(const float* __restrict__ x,
                           const float* __restrict__ W0, const float* __restrict__ W1,
                           const float* __restrict__ W2, const float* __restrict__ pW,
                           half_t* __restrict__ xh, half_t* __restrict__ WT,
                           half_t* __restrict__ pWT, unsigned* __restrict__ e2mu) {
  int bx = blockIdx.x, t = threadIdx.x;
  if (bx < 3072) {
    int idx = (bx * 256 + t) * 4;
    float4 v = *(const float4*)(x + idx);
    f16x4 h;
    h[0] = (half_t)v.x; h[1] = (half_t)v.y; h[2] = (half_t)v.z; h[3] = (half_t)v.w;
    *(f16x4*)(xh + idx) = h;
    return;
  }
  int idx2 = bx - 3072;
  if (idx2 == 0 && t < 3) e2mu[t] = 0x00800000u;   // enc(-FLT_MAX)
  int y = idx2 >> 9;
  int idx = ((idx2 & 511) << 8) + t;
  if (y < 3) {
    const float* W = (y == 0) ? W0 : (y == 1) ? W1 : W2;
    int k = idx >> 8, n = idx & 255;
    WT[(size_t)y * DD * IN_DIM + (size_t)n * IN_DIM + k] = (half_t)W[idx];
  } else if (idx < DD * OUT_DIM) {
    int k = idx >> 7, o = idx & 127;
    pWT[(size_t)o * DD + k] = (half_t)pW[idx];
  }
}

// ---------------- GEMM1 + fused e-scores + fused e2-max + column exp tables ----------------
// eb1[j] = exp2(e2[j]), eb2[j] = exp2(0.2*e2[j]) (log2-scaled e2), per view.
__global__ __launch_bounds__(256, 2) void gemm1_kernel(
    const half_t* __restrict__ xh, const half_t* __restrict__ WT,
    const float* __restrict__ as0, const float* __restrict__ as1, const float* __restrict__ as2,
    const float* __restrict__ ad0, const float* __restrict__ ad1, const float* __restrict__ ad2,
    half_t* __restrict__ hT, float* __restrict__ e1,
    float* __restrict__ eb1, float* __restrict__ eb2, unsigned* __restrict__ e2mu) {
  int v = blockIdx.y;
  int i0 = blockIdx.x * 64;
  int t = threadIdx.x;
  int lane = t & 63, w = t >> 6;
  int lr = lane & 15, lg = lane >> 4;
  const half_t* Wv = WT + (size_t)v * DD * IN_DIM;
  const float* asv = (v == 0) ? as0 : (v == 1) ? as1 : as2;
  const float* adv = (v == 0) ? ad0 : (v == 1) ? ad1 : ad2;
  f32x4 acc[4][4] = {};
  for (int kt = 0; kt < 16; ++kt) {
    int k = kt * 32 + lg * 8;
    f16x8 af[4], bf[4];
#pragma unroll
    for (int mf = 0; mf < 4; ++mf)
      af[mf] = *(const f16x8*)(xh + (size_t)(i0 + mf * 16 + lr) * IN_DIM + k);
#pragma unroll
    for (int nf = 0; nf < 4; ++nf)
      bf[nf] = *(const f16x8*)(Wv + (size_t)(w * 64 + nf * 16 + lr) * IN_DIM + k);
#pragma unroll
    for (int mf = 0; mf < 4; ++mf)
#pragma unroll
      for (int nf = 0; nf < 4; ++nf)
        acc[mf][nf] = mfma16(af[mf], bf[nf], acc[mf][nf]);
  }
  __shared__ half_t tr[4][64 * 64];
  __shared__ float ep1[4][64], ep2[4][64];
  char* trw = (char*)tr[w];
#pragma unroll
  for (int mf = 0; mf < 4; ++mf)
#pragma unroll
    for (int nf = 0; nf < 4; ++nf)
#pragma unroll
      for (int r = 0; r < 4; ++r) {
        int dl = nf * 16 + lr;
        int il = mf * 16 + lg * 4 + r;
        unsigned addr = (unsigned)((dl * 128 + il * 2) ^ ((dl & 7) << 4));
        *(half_t*)(trw + addr) = (half_t)acc[mf][nf][r];
      }
  float as_c[4], ad_c[4];
#pragma unroll
  for (int nf = 0; nf < 4; ++nf) {
    int col = w * 64 + nf * 16 + lr;
    as_c[nf] = asv[col];
    ad_c[nf] = adv[col];
  }
#pragma unroll
  for (int mf = 0; mf < 4; ++mf)
#pragma unroll
    for (int r = 0; r < 4; ++r) {
      float p1 = 0.f, p2 = 0.f;
#pragma unroll
      for (int nf = 0; nf < 4; ++nf) {
        p1 = fmaf(acc[mf][nf][r], as_c[nf], p1);
        p2 = fmaf(acc[mf][nf][r], ad_c[nf], p2);
      }
      p1 += __shfl_xor(p1, 1); p1 += __shfl_xor(p1, 2);
      p1 += __shfl_xor(p1, 4); p1 += __shfl_xor(p1, 8);
      p2 += __shfl_xor(p2, 1); p2 += __shfl_xor(p2, 2);
      p2 += __shfl_xor(p2, 4); p2 += __shfl_xor(p2, 8);
      if (lr == 0) {
        int il = mf * 16 + lg * 4 + r;
        ep1[w][il] = p1;
        ep2[w][il] = p2;
      }
    }
  __syncthreads();
  half_t* hTv = hT + (size_t)v * DD * NN;
#pragma unroll
  for (int c = 0; c < 8; ++c) {
    unsigned addr = (unsigned)((lane * 128 + c * 16) ^ ((lane & 7) << 4));
    f16x8 val = *(const f16x8*)(trw + addr);
    *(f16x8*)(hTv + (size_t)(w * 64 + lane) * NN + i0 + c * 8) = val;
  }
  if (t < 64) {
    float e1v = LOG2E * (ep1[0][t] + ep1[1][t] + ep1[2][t] + ep1[3][t]);
    float e2v = LOG2E * (ep2[0][t] + ep2[1][t] + ep2[2][t] + ep2[3][t]);
    e1[v * NN + i0 + t] = e1v;
    eb1[v * NN + i0 + t] = exp2f(e2v);
    eb2[v * NN + i0 + t] = exp2f(0.2f * e2v);
    float m = e2v;
    m = fmaxf(m, __shfl_xor(m, 1));  m = fmaxf(m, __shfl_xor(m, 2));
    m = fmaxf(m, __shfl_xor(m, 4));  m = fmaxf(m, __shfl_xor(m, 8));
    m = fmaxf(m, __shfl_xor(m, 16)); m = fmaxf(m, __shfl_xor(m, 32));
    if (t == 0) atomicMax(e2mu + v, enc_f(m));
  }
}

// ---------------- fused GAT aggregation: counted-vmcnt + XCD swizzle + separable exp ----------------
// P[i][j] = adj ? (s1>0 ? A1[i]*B1[j] : A2[i]*B2[j]) : 0  -- no transcendentals
// in the inner loop. s1>0 <=> B1[j] > exp2(-e1[i]) (monotone).
__global__ __launch_bounds__(256, 2) void gat_kernel(
    const int* __restrict__ adj0, const int* __restrict__ adj1, const int* __restrict__ adj2,
    const half_t* __restrict__ hT,
    const float* __restrict__ e1g, const float* __restrict__ eb1g,
    const float* __restrict__ eb2g,
    const unsigned* __restrict__ e2mu, half_t* __restrict__ pacc, float* __restrict__ pl) {
  // XCD-aware remap (1152 % 8 == 0 -> bijective)
  int orig = blockIdx.x;
  int swz = (orig & 7) * 144 + (orig >> 3);
  int v = swz / (96 * SPLIT);
  int rem = swz - v * (96 * SPLIT);
  int s = rem / 96;
  int i0 = (rem - s * 96) * 64;

  const int* __restrict__ adjv = (v == 0) ? adj0 : (v == 1) ? adj1 : adj2;
  int t = threadIdx.x;
  int lane = t & 63, w = t >> 6;
  int lr = lane & 15, lg = lane >> 4;
  int jq = t & 15, rg = t >> 4;

  __shared__ half_t hbuf0[DD * 64];   // 32 KB
  __shared__ half_t hbuf1[DD * 64];   // 32 KB
  __shared__ half_t P0[64 * 64];      // 8 KB
  __shared__ half_t P1[64 * 64];      // 8 KB

  const half_t* hTv = hT + (size_t)v * DD * NN;
  const float* eb1v = eb1g + v * NN;
  const float* eb2v = eb2g + v * NN;
  const int jbase = s * JT * 64;

  // per-row constants: A1 = exp2(e1-m), A2 = exp2(0.2*e1-m), thr = exp2(-e1)
  float A1r[4], A2r[4], thr[4];
  float e2mL = dec_f(e2mu[v]);
#pragma unroll
  for (int it = 0; it < 4; ++it) {
    float e1i = e1g[v * NN + i0 + it * 16 + rg];
    float sm = e1i + e2mL;
    float mr = fmaxf(sm, 0.2f * sm);   // lrelu upper bound of row max (log2 units)
    A1r[it] = exp2f(e1i - mr);
    A2r[it] = exp2f(0.2f * e1i - mr);
    thr[it] = exp2f(-e1i);
  }

  f32x4 acc[4][4] = {};
  float lpart[4] = {0.f, 0.f, 0.f, 0.f};

  int sub = lane >> 3;
  int c_src = (lane & 7) ^ sub;
  auto gload = [&](half_t* hb, int jt) {
    int j0 = jbase + jt * 64;
#pragma unroll
    for (int q = 0; q < 8; ++q) {
      const half_t* gp = hTv + (size_t)(w * 64 + q * 8 + sub) * NN + j0 + c_src * 8;
      half_t* lp = hb + (w * 8 + q) * 512;
      __builtin_amdgcn_global_load_lds(
          (const __attribute__((address_space(1))) int*)gp,
          (__attribute__((address_space(3))) int*)lp, 16, 0, 0);
    }
  };
  auto load_adj = [&](int4 (&aw)[4], int jt) {
    int j0 = jbase + jt * 64;
#pragma unroll
    for (int it = 0; it < 4; ++it)
      aw[it] = *(const int4*)(adjv + (size_t)(i0 + it * 16 + rg) * NN + j0 + jq * 4);
  };
  auto comp_p = [&](const int4 (&aw)[4], const float4& b1q, const float4& b2q, char* pb) {
    float b1[4] = {b1q.x, b1q.y, b1q.z, b1q.w};
    float b2[4] = {b2q.x, b2q.y, b2q.z, b2q.w};
#pragma unroll
    for (int it = 0; it < 4; ++it) {
      int il = it * 16 + rg;
      int a4[4] = {aw[it].x, aw[it].y, aw[it].z, aw[it].w};
      f16x4 ph;
      float s0 = 0.f, s1 = 0.f;
#pragma unroll
      for (int c = 0; c < 4; ++c) {
        bool pos = b1[c] > thr[it];
        float A = pos ? A1r[it] : A2r[it];
        float B = pos ? b1[c] : b2[c];
        float p = (a4[c] > 0) ? A * B : 0.f;
        if (c & 1) s1 += p; else s0 += p;
        ph[c] = (half_t)p;
      }
      lpart[it] += s0 + s1;
      unsigned addr = (unsigned)((il * 128 + jq * 8) ^ ((il & 7) << 4));
      *(f16x4*)(pb + addr) = ph;
    }
  };
  auto do_mfma = [&](const char* pb, const half_t* hb) {
    __builtin_amdgcn_s_setprio(1);
#pragma unroll
    for (int kf = 0; kf < 2; ++kf) {
      f16x8 bfr[4];
#pragma unroll
      for (int nf = 0; nf < 4; ++nf) {
        int d = w * 64 + nf * 16 + lr;
        unsigned ba = (unsigned)(d * 128 + ((kf * 64 + lg * 16) ^ ((lr & 7) << 4)));
        bfr[nf] = *(const f16x8*)((const char*)hb + ba);
      }
#pragma unroll
      for (int mf = 0; mf < 4; ++mf) {
        int row = mf * 16 + lr;
        unsigned pa_ = (unsigned)((row * 128 + kf * 64 + lg * 16) ^ ((row & 7) << 4));
        f16x8 af = *(const f16x8*)(pb + pa_);
#pragma unroll
        for (int nf = 0; nf < 4; ++nf)
          acc[mf][nf] = mfma16(af, bfr[nf], acc[mf][nf]);
      }
    }
    __builtin_amdgcn_s_setprio(0);
  };

  int4 awA[4], awB[4];
  float4 b1A, b2A, b1B, b2B;

  // prologue: adj(0)/B(0) FIRST (oldest), then gload(0), then adj(1)/B(1).
  load_adj(awA, 0);
  b1A = *(const float4*)(eb1v + jbase + jq * 4);
  b2A = *(const float4*)(eb2v + jbase + jq * 4);
  SBAR();
  gload(hbuf0, 0);
  SBAR();
  load_adj(awB, 1);
  b1B = *(const float4*)(eb1v + jbase + 64 + jq * 4);
  b2B = *(const float4*)(eb2v + jbase + 64 + jq * 4);
  SBAR();

  // per region: outstanding at VWAIT = 8 gload + 4 adj + 2 B = 14 -> VWAIT(6)
#define REGION_F(T, AWc, B1c, B2c, Pc, Hc, Hn)                       \
  {                                                                  \
    comp_p(AWc, B1c, B2c, (char*)(Pc));                              \
    LBAR();                                                          \
    SBAR();                                                          \
    VWAIT(6);                                                        \
    SBAR();                                                          \
    gload(Hn, (T) + 1);                                              \
    SBAR();                                                          \
    load_adj(AWc, (T) + 2);                                          \
    B1c = *(const float4*)(eb1v + jbase + ((T) + 2) * 64 + jq * 4);  \
    B2c = *(const float4*)(eb2v + jbase + ((T) + 2) * 64 + jq * 4);  \
    SBAR();                                                          \
    do_mfma((char*)(Pc), Hc);                                        \
  }

  for (int tt = 0; tt < JT - 2; tt += 2) {
    REGION_F(tt,     awA, b1A, b2A, P0, hbuf0, hbuf1);
    REGION_F(tt + 1, awB, b1B, b2B, P1, hbuf1, hbuf0);
  }
  // region JT-2: stage gload(JT-1); no adj refill.
  {
    comp_p(awA, b1A, b2A, (char*)P0);
    LBAR();
    SBAR();
    VWAIT(6);
    SBAR();
    gload(hbuf1, JT - 1);
    SBAR();
    do_mfma((char*)P0, hbuf0);
  }
  // region JT-1: drain fully.
  {
    comp_p(awB, b1B, b2B, (char*)P1);
    LBAR();
    SBAR();
    VWAIT(0);
    SBAR();
    do_mfma((char*)P1, hbuf1);
  }
#undef REGION_F

  // row sums: reduce over jq within each 16-lane group, write pl directly
  size_t sl = (size_t)v * SPLIT + s;
#pragma unroll
  for (int it = 0; it < 4; ++it) {
    float ssum = lpart[it];
    ssum += __shfl_xor(ssum, 1); ssum += __shfl_xor(ssum, 2);
    ssum += __shfl_xor(ssum, 4); ssum += __shfl_xor(ssum, 8);
    if (jq == 0) pl[sl * NN + i0 + it * 16 + rg] = ssum;
  }

  half_t* pa = pacc + sl * (size_t)NN * DD;
#pragma unroll
  for (int mf = 0; mf < 4; ++mf)
#pragma unroll
    for (int r = 0; r < 4; ++r) {
      int il = mf * 16 + lg * 4 + r;
#pragma unroll
      for (int nf = 0; nf < 4; ++nf)
        pa[(size_t)(i0 + il) * DD + w * 64 + nf * 16 + lr] = (half_t)acc[mf][nf][r];
    }
}

// ---------------- proj + LN + weighted combine (fused slice-combine) ----------------
__global__ __launch_bounds__(64) void proj_kernel(
    const half_t* __restrict__ pacc, const float* __restrict__ pl,
    const half_t* __restrict__ pWT,
    const float* __restrict__ proj_b, const float* __restrict__ ln_g,
    const float* __restrict__ ln_b, const float* __restrict__ alpha,
    float* __restrict__ out) {
  int i0 = blockIdx.x * 16;
  int t = threadIdx.x;
  int lr = t & 15, lg = t >> 4;
  float a0 = alpha[0], a1 = alpha[1], a2 = alpha[2];
  float am = fmaxf(a0, fmaxf(a1, a2));
  float x0 = __expf(a0 - am), x1 = __expf(a1 - am), x2 = __expf(a2 - am);
  float inv = 1.f / (x0 + x1 + x2);
  float wv[3] = {x0 * inv, x1 * inv, x2 * inv};
  __shared__ float rlv[3][16];
  if (t < 48) {
    int v = t >> 4, i = t & 15;
    float l = 0.f;
#pragma unroll
    for (int s = 0; s < SPLIT; ++s)
      l += pl[((size_t)v * SPLIT + s) * NN + i0 + i];
    rlv[v][i] = (l > 0.f) ? 1.f / l : 0.f;
  }
  float pb[8], gg[8], bb[8];
#pragma unroll
  for (int nf = 0; nf < 8; ++nf) {
    pb[nf] = proj_b[nf * 16 + lr];
    gg[nf] = ln_g[nf * 16 + lr];
    bb[nf] = ln_b[nf * 16 + lr];
  }
  __syncthreads();
  f32x4 zacc[8] = {};
  for (int v = 0; v < 3; ++v) {
    float rl = rlv[v][lr];
    f32x4 yac[8] = {};
    const half_t* p0 = pacc + (((size_t)v * SPLIT + 0) * NN + i0 + lr) * DD;
    const half_t* p1 = pacc + (((size_t)v * SPLIT + 1) * NN + i0 + lr) * DD;
    const half_t* p2 = pacc + (((size_t)v * SPLIT + 2) * NN + i0 + lr) * DD;
    const half_t* p3 = pacc + (((size_t)v * SPLIT + 3) * NN + i0 + lr) * DD;
    for (int kt = 0; kt < 8; ++kt) {
      int k = kt * 32 + lg * 8;
      f16x8 s0 = *(const f16x8*)(p0 + k);
      f16x8 s1 = *(const f16x8*)(p1 + k);
      f16x8 s2 = *(const f16x8*)(p2 + k);
      f16x8 s3 = *(const f16x8*)(p3 + k);
      f16x8 af;
#pragma unroll
      for (int e = 0; e < 8; ++e)
        af[e] = (half_t)((((float)s0[e] + (float)s1[e]) +
                          ((float)s2[e] + (float)s3[e])) * rl);
#pragma unroll
      for (int nf = 0; nf < 8; ++nf) {
        f16x8 bf = *(const f16x8*)(pWT + (size_t)(nf * 16 + lr) * DD + k);
        yac[nf] = mfma16(af, bf, yac[nf]);
      }
    }
#pragma unroll
    for (int r = 0; r < 4; ++r) {
      float ssum = 0.f, q = 0.f;
#pragma unroll
      for (int nf = 0; nf < 8; ++nf) {
        float y = yac[nf][r] + pb[nf];
        yac[nf][r] = y;
        ssum += y; q += y * y;
      }
      ssum += __shfl_xor(ssum, 1); ssum += __shfl_xor(ssum, 2);
      ssum += __shfl_xor(ssum, 4); ssum += __shfl_xor(ssum, 8);
      q += __shfl_xor(q, 1); q += __shfl_xor(q, 2);
      q += __shfl_xor(q, 4); q += __shfl_xor(q, 8);
      float mean = ssum * (1.f / 128.f);
      float var = q * (1.f / 128.f) - mean * mean;
      float rstd = rsqrtf(var + 1e-5f);
      float wvv = wv[v];
#pragma unroll
      for (int nf = 0; nf < 8; ++nf)
        zacc[nf][r] += wvv * (yac[nf][r] - mean) * rstd;
    }
  }
#pragma unroll
  for (int nf = 0; nf < 8; ++nf)
#pragma unroll
    for (int r = 0; r < 4; ++r) {
      int row = i0 + lg * 4 + r;
      float z = zacc[nf][r] * gg[nf] + bb[nf];
      if (!isfinite(z)) z = 0.f;
      out[(size_t)row * OUT_DIM + nf * 16 + lr] = z;
    }
  if (blockIdx.x == 0 && t < 3) out[(size_t)NN * OUT_DIM + t] = wv[t];
}

// ---------------- launch ----------------
extern "C" void kernel_launch(void* const* d_in, const int* in_sizes, int n_in,
                              void* d_out, int out_size, void* d_ws, size_t ws_size,
                              hipStream_t stream) {
  const float* x      = (const float*)d_in[0];
  const int*   adj_cf = (const int*)d_in[1];
  const int*   adj_or = (const int*)d_in[2];
  const int*   adj_pe = (const int*)d_in[3];
  const float* W_cf   = (const float*)d_in[4];
  const float* as_cf  = (const float*)d_in[5];
  const float* ad_cf  = (const float*)d_in[6];
  const float* W_or   = (const float*)d_in[7];
  const float* as_or  = (const float*)d_in[8];
  const float* ad_or  = (const float*)d_in[9];
  const float* W_pe   = (const float*)d_in[10];
  const float* as_pe  = (const float*)d_in[11];
  const float* ad_pe  = (const float*)d_in[12];
  const float* proj_W = (const float*)d_in[13];
  const float* proj_b = (const float*)d_in[14];
  const float* ln_g   = (const float*)d_in[15];
  const float* ln_b   = (const float*)d_in[16];
  const float* alpha  = (const float*)d_in[17];

  char* ws = (char*)d_ws;
  half_t*   xh     = (half_t*)(ws + 0);          // 6291456
  half_t*   WT     = (half_t*)(ws + 6291456);    // 786432
  half_t*   pWT    = (half_t*)(ws + 7077888);    // 65536
  half_t*   hT     = (half_t*)(ws + 7143424);    // 9437184
  float*    e1     = (float*)(ws + 16580608);    // 73728
  float*    eb1    = (float*)(ws + 16654336);    // 73728
  float*    eb2    = (float*)(ws + 16728064);    // 73728
  unsigned* e2mu   = (unsigned*)(ws + 16801792); // 64
  half_t*   pacc   = (half_t*)(ws + 16801856);   // 37748736
  float*    pl     = (float*)(ws + 54550592);    // 294912

  cvt_kernel<<<5120, 256, 0, stream>>>(x, W_cf, W_or, W_pe, proj_W, xh, WT, pWT, e2mu);
  gemm1_kernel<<<dim3(96, 3), 256, 0, stream>>>(xh, WT, as_cf, as_or, as_pe,
                                                ad_cf, ad_or, ad_pe, hT, e1,
                                                eb1, eb2, e2mu);
  gat_kernel<<<96 * SPLIT * 3, 256, 0, stream>>>(adj_cf, adj_or, adj_pe, hT,
                                                 e1, eb1, eb2, e2mu, pacc, pl);
  proj_kernel<<<384, 64, 0, stream>>>(pacc, pl, pWT, proj_b, ln_g, ln_b, alpha,
                                      (float*)d_out);
}